// Round 5
// baseline (72.824 us; speedup 1.0000x reference)
//
#include <hip/hip_runtime.h>
#include <stdint.h>

constexpr int B_ = 64;
constexpr int P_ = 65536;
constexpr int NEGPOS_ = 7;
constexpr int NBINS = 512;          // linear bins of d = c1 - c0 over [-5, 5]
constexpr int CHUNK = 2048;         // anchors per K1 block (8/thread)
constexpr int CPR = P_ / CHUNK;     // 32
constexpr int NBLK = B_ * CPR;      // 2048
constexpr int K2B = 512;            // K2 grid

__device__ __forceinline__ int bin_of(float d) {
    int b = (int)fmaf(d, 51.2f, 256.0f);
    return b < 0 ? 0 : (b > NBINS - 1 ? NBINS - 1 : b);
}
__device__ __forceinline__ float softplus(float x) {
    return fmaxf(x, 0.f) + log1pf(expf(-fabsf(x)));
}
__device__ __forceinline__ float smooth_l1(float t, float p) {
    float ad = fabsf(t - p);
    return ad < 1.0f ? 0.5f * ad * ad : ad - 0.5f;
}

// Workspace layout. [OFF_CTR, ZERO_BYTES) is memset to 0 each call; everything
// else is fully overwritten before being read.
constexpr size_t OFF_CTR   = 0;                                   // u32 (+pad)
constexpr size_t OFF_RHC   = 128;                                 // 64*512 u32
constexpr size_t OFF_RHS   = OFF_RHC + (size_t)B_ * NBINS * 4;    // 64*512 f32
constexpr size_t ZERO_BYTES= OFF_RHS + (size_t)B_ * NBINS * 4;    // 262272
constexpr size_t OFF_LCE   = ZERO_BYTES;                          // NBLK f32
constexpr size_t OFF_CPOS  = OFF_LCE + (size_t)NBLK * 4;          // NBLK u32
constexpr size_t OFF_BPB   = OFF_CPOS + (size_t)NBLK * 4;         // K2B float4
constexpr size_t OFF_BCB   = OFF_BPB + (size_t)K2B * 16;          // K2B uint4
constexpr size_t OFF_ROWS2 = OFF_BCB + (size_t)K2B * 16;          // 64 f32
constexpr size_t OFF_LIST  = OFF_ROWS2 + 256;                     // up to B_*P_ u32

// ---- K1: dense stream over label+conf only --------------------------------------
__global__ __launch_bounds__(256, 8) void mb_pass1(
    const float* __restrict__ conf, const int* __restrict__ label,
    float* __restrict__ lceB, unsigned* __restrict__ cposB,
    unsigned* __restrict__ rowhc, float* __restrict__ rowhs,
    unsigned* __restrict__ list, unsigned* __restrict__ ctr)
{
    __shared__ unsigned hcnt[NBINS];
    __shared__ float    hsum[NBINS];
    __shared__ unsigned lpos[CHUNK];      // compacted positive anchor indices
    __shared__ unsigned lcount, gbase;
    __shared__ float    redf[4];
    __shared__ unsigned redu[4];

    const int blk = blockIdx.x, t = threadIdx.x;
    const int row = blk / CPR, chunk = blk % CPR;

    hcnt[2 * t] = 0u; hcnt[2 * t + 1] = 0u;
    hsum[2 * t] = 0.f; hsum[2 * t + 1] = 0.f;
    if (t == 0) lcount = 0u;
    __syncthreads();

    const int base = row * P_ + chunk * CHUNK;
    float lce = 0.f; unsigned cp = 0;

    auto proc = [&](int lab, float d, int idx) {
        if (lab != 0) {
            cp++;
            lce += softplus(-d);                       // lse - c1
            lpos[atomicAdd(&lcount, 1u)] = (unsigned)idx;
        } else {
            const int b = bin_of(d);
            atomicAdd(&hcnt[b], 1u);
            atomicAdd(&hsum[b], softplus(d));          // lse - c0
        }
    };

    #pragma unroll
    for (int g = 0; g < 2; ++g) {
        const int a = base + g * 1024 + t * 4;         // 4 consecutive anchors
        const int4   lab = *(const int4*)(label + a);
        const float4 cA  = *(const float4*)(conf + 2 * a);
        const float4 cB  = *(const float4*)(conf + 2 * a + 4);
        proc(lab.x, cA.y - cA.x, a + 0);
        proc(lab.y, cA.w - cA.z, a + 1);
        proc(lab.z, cB.y - cB.x, a + 2);
        proc(lab.w, cB.w - cB.z, a + 3);
    }

    #pragma unroll
    for (int o = 32; o > 0; o >>= 1) {
        lce += __shfl_down(lce, o);
        cp  += __shfl_down(cp, o);
    }
    const int wid = t >> 6;
    if ((t & 63) == 0) { redf[wid] = lce; redu[wid] = cp; }
    __syncthreads();
    if (t == 0) {
        lceB[blk]  = redf[0] + redf[1] + redf[2] + redf[3];
        cposB[blk] = redu[0] + redu[1] + redu[2] + redu[3];
        gbase = atomicAdd(ctr, lcount);                // one global atomic per block
    }
    __syncthreads();

    // coalesced copy-out of this block's positives
    const unsigned n = lcount, gb = gbase;
    for (unsigned s = t; s < n; s += 256) list[gb + s] = lpos[s];

    // flush LDS hist into the per-row global hist (device-scope atomics)
    unsigned* rc = rowhc + (size_t)row * NBINS;
    float*    rs = rowhs + (size_t)row * NBINS;
    {
        unsigned c = hcnt[t];
        if (c) { atomicAdd(&rc[t], c); atomicAdd(&rs[t], hsum[t]); }
        c = hcnt[t + 256];
        if (c) { atomicAdd(&rc[t + 256], c); atomicAdd(&rs[t + 256], hsum[t + 256]); }
    }
}

// ---- K2: compacted positives, all lanes active ----------------------------------
__global__ __launch_bounds__(256) void mb_pass2(
    const float* __restrict__ boxes_p, const float* __restrict__ kpts_p,
    const float* __restrict__ dpth_p,  const float* __restrict__ boxes_t,
    const float* __restrict__ kypts_t, const float* __restrict__ dpths_t,
    const unsigned* __restrict__ list, const unsigned* __restrict__ ctr,
    float4* __restrict__ bpb, uint4* __restrict__ bcb)
{
    const unsigned npos = *ctr;
    float lb = 0.f, ll = 0.f, ld = 0.f;
    unsigned cb = 0, cl = 0, cd = 0;

    for (unsigned g = blockIdx.x * 256u + threadIdx.x; g < npos; g += 256u * K2B) {
        const unsigned i = list[g];
        const float4 bt = ((const float4*)boxes_t)[i];
        const float4 bp = ((const float4*)boxes_p)[i];
        if (!__builtin_isnan(bt.x)) { cb++; lb += smooth_l1(bt.x, bp.x); }
        if (!__builtin_isnan(bt.y)) { cb++; lb += smooth_l1(bt.y, bp.y); }
        if (!__builtin_isnan(bt.z)) { cb++; lb += smooth_l1(bt.z, bp.z); }
        if (!__builtin_isnan(bt.w)) { cb++; lb += smooth_l1(bt.w, bp.w); }
        const float2* kt = (const float2*)kypts_t + (size_t)i * 5;
        const float2* kp = (const float2*)kpts_p  + (size_t)i * 5;
        #pragma unroll
        for (int e = 0; e < 5; ++e) {
            const float2 t2 = kt[e], p2 = kp[e];
            if (!__builtin_isnan(t2.x)) { cl++; ll += smooth_l1(t2.x, p2.x); }
            if (!__builtin_isnan(t2.y)) { cl++; ll += smooth_l1(t2.y, p2.y); }
        }
        const float2 dt = ((const float2*)dpths_t)[i];
        const float2 dp = ((const float2*)dpth_p)[i];
        if (!__builtin_isnan(dt.x)) { cd++; ld += smooth_l1(dt.x, dp.x); }
        if (!__builtin_isnan(dt.y)) { cd++; ld += smooth_l1(dt.y, dp.y); }
    }

    #pragma unroll
    for (int o = 32; o > 0; o >>= 1) {
        lb += __shfl_down(lb, o); ll += __shfl_down(ll, o); ld += __shfl_down(ld, o);
        cb += __shfl_down(cb, o); cl += __shfl_down(cl, o); cd += __shfl_down(cd, o);
    }
    __shared__ float rf[4][3];
    __shared__ unsigned ru[4][3];
    const int wid = threadIdx.x >> 6;
    if ((threadIdx.x & 63) == 0) {
        rf[wid][0] = lb; rf[wid][1] = ll; rf[wid][2] = ld;
        ru[wid][0] = cb; ru[wid][1] = cl; ru[wid][2] = cd;
    }
    __syncthreads();
    if (threadIdx.x == 0) {
        float F0 = 0, F1 = 0, F2 = 0; unsigned U0 = 0, U1 = 0, U2 = 0;
        #pragma unroll
        for (int w = 0; w < 4; ++w) {
            F0 += rf[w][0]; F1 += rf[w][1]; F2 += rf[w][2];
            U0 += ru[w][0]; U1 += ru[w][1]; U2 += ru[w][2];
        }
        bpb[blockIdx.x] = make_float4(F0, F1, F2, 0.f);
        bcb[blockIdx.x] = make_uint4(U0, U1, U2, 0u);
    }
}

// ---- K3: per-row top-k sum from the 64x512 row histograms -----------------------
__global__ __launch_bounds__(512) void mb_select(
    const unsigned* __restrict__ rowhc, const float* __restrict__ rowhs,
    const unsigned* __restrict__ cposB, float* __restrict__ rowS2)
{
    const int r = blockIdx.x, j = threadIdx.x;
    const unsigned c = rowhc[(size_t)r * NBINS + j];
    const float    s = rowhs[(size_t)r * NBINS + j];

    __shared__ unsigned sc[NBINS];
    __shared__ float    ss[NBINS];
    sc[j] = c; ss[j] = s;
    __syncthreads();
    for (int off = 1; off < NBINS; off <<= 1) {      // inclusive suffix scan
        const unsigned ca = (j + off < NBINS) ? sc[j + off] : 0u;
        const float    sa = (j + off < NBINS) ? ss[j + off] : 0.f;
        __syncthreads();
        sc[j] += ca; ss[j] += sa;
        __syncthreads();
    }
    const unsigned Tj = sc[j]; const float Sj = ss[j];
    const unsigned T0 = sc[0]; const float S0 = ss[0];

    __shared__ unsigned snp;
    if (j < 64) {
        unsigned v = (j < CPR) ? cposB[(size_t)r * CPR + j] : 0u;
        #pragma unroll
        for (int o = 32; o > 0; o >>= 1) v += __shfl_down(v, o);
        if (j == 0) snp = v;
    }
    __syncthreads();

    long long k = (long long)NEGPOS_ * (long long)snp;
    if (k > P_ - 1) k = P_ - 1;

    if (k <= 0)             { if (j == 0) rowS2[r] = 0.f; return; }
    if ((long long)T0 <= k) { if (j == 0) rowS2[r] = S0;  return; }

    const unsigned above = Tj - c;       // strictly-higher-bin count
    if ((long long)above < k && k <= (long long)Tj) {   // unique boundary thread
        const unsigned rr = (unsigned)(k - above);
        rowS2[r] = (Sj - s) + (c ? s * (float)rr / (float)c : 0.f);
    }
}

// ---- K4: finalize ---------------------------------------------------------------
__global__ __launch_bounds__(256) void mb_final(
    const float* __restrict__ lceB, const unsigned* __restrict__ cposB,
    const float4* __restrict__ bpb, const uint4* __restrict__ bcb,
    const float* __restrict__ rowS2, float* __restrict__ out)
{
    const int t = threadIdx.x;
    float ce = 0.f; unsigned np = 0;
    for (int i = t; i < NBLK; i += 256) { ce += lceB[i]; np += cposB[i]; }
    float f0 = 0, f1 = 0, f2 = 0; unsigned u0 = 0, u1 = 0, u2 = 0;
    for (int i = t; i < K2B; i += 256) {
        const float4 bp = bpb[i]; const uint4 bc = bcb[i];
        f0 += bp.x; f1 += bp.y; f2 += bp.z;
        u0 += bc.x; u1 += bc.y; u2 += bc.z;
    }
    float s2 = (t < B_) ? rowS2[t] : 0.f;
    #pragma unroll
    for (int o = 32; o > 0; o >>= 1) {
        ce += __shfl_down(ce, o); s2 += __shfl_down(s2, o);
        f0 += __shfl_down(f0, o); f1 += __shfl_down(f1, o); f2 += __shfl_down(f2, o);
        np += __shfl_down(np, o);
        u0 += __shfl_down(u0, o); u1 += __shfl_down(u1, o); u2 += __shfl_down(u2, o);
    }
    __shared__ float rf[4][5];
    __shared__ unsigned ru[4][4];
    const int wid = t >> 6;
    if ((t & 63) == 0) {
        rf[wid][0] = f0; rf[wid][1] = f1; rf[wid][2] = f2; rf[wid][3] = ce; rf[wid][4] = s2;
        ru[wid][0] = u0; ru[wid][1] = u1; ru[wid][2] = u2; ru[wid][3] = np;
    }
    __syncthreads();
    if (t == 0) {
        float F0 = 0, F1 = 0, F2 = 0, CE = 0, S2 = 0;
        unsigned U0 = 0, U1 = 0, U2 = 0, NP = 0;
        #pragma unroll
        for (int w = 0; w < 4; ++w) {
            F0 += rf[w][0]; F1 += rf[w][1]; F2 += rf[w][2]; CE += rf[w][3]; S2 += rf[w][4];
            U0 += ru[w][0]; U1 += ru[w][1]; U2 += ru[w][2]; NP += ru[w][3];
        }
        const float nl = U0 ? (float)U0 : 1.f;
        const float n1 = U1 ? (float)U1 : 1.f;
        const float nd = U2 ? (float)U2 : 1.f;
        const float n  = NP ? (float)NP : 1.f;
        out[0] = F0 / nl;          // loss_l / nl
        out[1] = (CE + S2) / n;    // loss_conf / n
        out[2] = F1 / n1;          // loss_landm / n1
        out[3] = F2 / nd;          // loss_dpth / ndpth
    }
}

extern "C" void kernel_launch(void* const* d_in, const int* in_sizes, int n_in,
                              void* d_out, int out_size, void* d_ws, size_t ws_size,
                              hipStream_t stream) {
    const float* boxes_p = (const float*)d_in[0];
    const float* conf_p  = (const float*)d_in[1];
    const float* kpts_p  = (const float*)d_in[2];
    const float* dpth_p  = (const float*)d_in[3];
    const float* boxes_t = (const float*)d_in[4];
    const float* kypts_t = (const float*)d_in[5];
    const float* dpths_t = (const float*)d_in[6];
    const int*   label   = (const int*)d_in[7];
    float* out = (float*)d_out;

    uint8_t* ws = (uint8_t*)d_ws;
    unsigned* ctr   = (unsigned*)(ws + OFF_CTR);
    unsigned* rowhc = (unsigned*)(ws + OFF_RHC);
    float*    rowhs = (float*)(ws + OFF_RHS);
    float*    lceB  = (float*)(ws + OFF_LCE);
    unsigned* cposB = (unsigned*)(ws + OFF_CPOS);
    float4*   bpb   = (float4*)(ws + OFF_BPB);
    uint4*    bcb   = (uint4*)(ws + OFF_BCB);
    float*    rowS2 = (float*)(ws + OFF_ROWS2);
    unsigned* list  = (unsigned*)(ws + OFF_LIST);

    hipMemsetAsync(d_ws, 0, ZERO_BYTES, stream);

    mb_pass1<<<NBLK, 256, 0, stream>>>(conf_p, label, lceB, cposB, rowhc, rowhs, list, ctr);

    mb_pass2<<<K2B, 256, 0, stream>>>(boxes_p, kpts_p, dpth_p, boxes_t, kypts_t, dpths_t,
                                      list, ctr, bpb, bcb);

    mb_select<<<B_, 512, 0, stream>>>(rowhc, rowhs, cposB, rowS2);

    mb_final<<<1, 256, 0, stream>>>(lceB, cposB, bpb, bcb, rowS2, out);
}

// Round 6
// 49.044 us; speedup vs baseline: 1.4849x; 1.4849x over previous
//
#include <hip/hip_runtime.h>
#include <stdint.h>

constexpr int B_ = 64;
constexpr int P_ = 65536;
constexpr int NEGPOS_ = 7;
constexpr int NBINS = 512;          // linear bins of d = c1 - c0 over [-5, 5]
constexpr int CHUNK = 2048;         // anchors per K1 block (8/thread)
constexpr int CPR = P_ / CHUNK;     // 32
constexpr int NBLK = B_ * CPR;      // 2048

__device__ __forceinline__ int bin_of(float d) {
    int b = (int)fmaf(d, 51.2f, 256.0f);
    return b < 0 ? 0 : (b > NBINS - 1 ? NBINS - 1 : b);
}
__device__ __forceinline__ float softplus(float x) {
    return fmaxf(x, 0.f) + log1pf(expf(-fabsf(x)));
}
__device__ __forceinline__ float smooth_l1(float t, float p) {
    float ad = fabsf(t - p);
    return ad < 1.0f ? 0.5f * ad * ad : ad - 0.5f;
}

// Workspace (every byte written before read, every call; NO memset needed)
constexpr size_t OFF_HIST  = 0;                                    // NBLK*NBINS uint2 (8 MB)
constexpr size_t OFF_BPART = OFF_HIST + (size_t)NBLK * NBINS * 8;  // NBLK float4
constexpr size_t OFF_BCNT  = OFF_BPART + (size_t)NBLK * 16;        // NBLK uint4
constexpr size_t OFF_ROWS2 = OFF_BCNT + (size_t)NBLK * 16;         // 64 f32

// ---- K1: dense stream + LDS-compacted positives + per-block hist ---------------
__global__ __launch_bounds__(256, 8) void mb_main(
    const float* __restrict__ conf,    const int* __restrict__ label,
    const float* __restrict__ boxes_p, const float* __restrict__ kpts_p,
    const float* __restrict__ dpth_p,  const float* __restrict__ boxes_t,
    const float* __restrict__ kypts_t, const float* __restrict__ dpths_t,
    uint2* __restrict__ hist, float4* __restrict__ bpart, uint4* __restrict__ bcnt)
{
    __shared__ unsigned hcnt[NBINS];
    __shared__ float    hsum[NBINS];
    __shared__ unsigned lpos[CHUNK];     // compacted positive indices (worst case all)
    __shared__ unsigned lcount;
    __shared__ float    redf[4][4];
    __shared__ unsigned redu[4][4];

    const int blk = blockIdx.x, t = threadIdx.x;
    const int row = blk / CPR, chunk = blk % CPR;

    hcnt[2 * t] = 0u; hcnt[2 * t + 1] = 0u;
    hsum[2 * t] = 0.f; hsum[2 * t + 1] = 0.f;
    if (t == 0) lcount = 0u;
    __syncthreads();

    const int base = row * P_ + chunk * CHUNK;
    float lce = 0.f; unsigned cp = 0;

    auto proc = [&](int lab, float d, int idx) {
        if (lab != 0) {
            cp++;
            lce += softplus(-d);                       // lse - c1
            lpos[atomicAdd(&lcount, 1u)] = (unsigned)idx;
        } else {
            const int b = bin_of(d);
            atomicAdd(&hcnt[b], 1u);
            atomicAdd(&hsum[b], softplus(d));          // lse - c0  (ds_add_f32)
        }
    };

    #pragma unroll
    for (int g = 0; g < 2; ++g) {
        const int a = base + g * 1024 + t * 4;         // 4 consecutive anchors
        const int4   lab = *(const int4*)(label + a);
        const float4 cA  = *(const float4*)(conf + 2 * a);
        const float4 cB  = *(const float4*)(conf + 2 * a + 4);
        proc(lab.x, cA.y - cA.x, a + 0);
        proc(lab.y, cA.w - cA.z, a + 1);
        proc(lab.z, cB.y - cB.x, a + 2);
        proc(lab.w, cB.w - cB.z, a + 3);
    }
    __syncthreads();   // lpos/lcount complete

    // positives: all lanes active, one batch of scattered loads
    float lb = 0.f, ll = 0.f, ld = 0.f;
    unsigned cb = 0, cl = 0, cd = 0;
    const unsigned n = lcount;
    for (unsigned s = t; s < n; s += 256) {
        const unsigned i = lpos[s];
        const float4 bt = ((const float4*)boxes_t)[i];
        const float4 bp = ((const float4*)boxes_p)[i];
        if (!__builtin_isnan(bt.x)) { cb++; lb += smooth_l1(bt.x, bp.x); }
        if (!__builtin_isnan(bt.y)) { cb++; lb += smooth_l1(bt.y, bp.y); }
        if (!__builtin_isnan(bt.z)) { cb++; lb += smooth_l1(bt.z, bp.z); }
        if (!__builtin_isnan(bt.w)) { cb++; lb += smooth_l1(bt.w, bp.w); }
        const float2* kt = (const float2*)kypts_t + (size_t)i * 5;
        const float2* kp = (const float2*)kpts_p  + (size_t)i * 5;
        #pragma unroll
        for (int e = 0; e < 5; ++e) {
            const float2 t2 = kt[e], p2 = kp[e];
            if (!__builtin_isnan(t2.x)) { cl++; ll += smooth_l1(t2.x, p2.x); }
            if (!__builtin_isnan(t2.y)) { cl++; ll += smooth_l1(t2.y, p2.y); }
        }
        const float2 dt = ((const float2*)dpths_t)[i];
        const float2 dp = ((const float2*)dpth_p)[i];
        if (!__builtin_isnan(dt.x)) { cd++; ld += smooth_l1(dt.x, dp.x); }
        if (!__builtin_isnan(dt.y)) { cd++; ld += smooth_l1(dt.y, dp.y); }
    }

    // block reduction of the 8 scalars (no atomics)
    #pragma unroll
    for (int o = 32; o > 0; o >>= 1) {
        lb  += __shfl_down(lb, o);  ll += __shfl_down(ll, o);
        ld  += __shfl_down(ld, o);  lce += __shfl_down(lce, o);
        cb  += __shfl_down(cb, o);  cl += __shfl_down(cl, o);
        cd  += __shfl_down(cd, o);  cp += __shfl_down(cp, o);
    }
    const int wid = t >> 6;
    if ((t & 63) == 0) {
        redf[wid][0] = lb; redf[wid][1] = ll; redf[wid][2] = ld; redf[wid][3] = lce;
        redu[wid][0] = cb; redu[wid][1] = cl; redu[wid][2] = cd; redu[wid][3] = cp;
    }
    __syncthreads();
    if (t == 0) {
        float f0 = 0, f1 = 0, f2 = 0, f3 = 0; unsigned u0 = 0, u1 = 0, u2 = 0, u3 = 0;
        #pragma unroll
        for (int w = 0; w < 4; ++w) {
            f0 += redf[w][0]; f1 += redf[w][1]; f2 += redf[w][2]; f3 += redf[w][3];
            u0 += redu[w][0]; u1 += redu[w][1]; u2 += redu[w][2]; u3 += redu[w][3];
        }
        bpart[blk] = make_float4(f0, f1, f2, f3);   // l_box, l_lm, l_dp, l_ce
        bcnt[blk]  = make_uint4(u0, u1, u2, u3);    // c_box, c_lm, c_dp, c_pos
    }

    // flush per-block packed hist (plain coalesced stores)
    uint2* hb = hist + (size_t)blk * NBINS;
    hb[t]       = make_uint2(hcnt[t],       __float_as_uint(hsum[t]));
    hb[t + 256] = make_uint2(hcnt[t + 256], __float_as_uint(hsum[t + 256]));
}

// ---- K2: per-row top-k sum from per-block hists ---------------------------------
__global__ __launch_bounds__(512) void mb_select(
    const uint2* __restrict__ hist, const uint4* __restrict__ bcnt,
    float* __restrict__ rowS2)
{
    const int r = blockIdx.x, j = threadIdx.x;

    unsigned c = 0; float s = 0.f;
    const uint2* hb = hist + (size_t)r * CPR * NBINS + j;
    #pragma unroll 8
    for (int ch = 0; ch < CPR; ++ch) {              // coalesced across j
        const uint2 v = hb[(size_t)ch * NBINS];
        c += v.x; s += __uint_as_float(v.y);
    }

    __shared__ unsigned sc[NBINS];
    __shared__ float    ss[NBINS];
    sc[j] = c; ss[j] = s;
    __syncthreads();
    for (int off = 1; off < NBINS; off <<= 1) {     // inclusive suffix scan
        const unsigned ca = (j + off < NBINS) ? sc[j + off] : 0u;
        const float    sa = (j + off < NBINS) ? ss[j + off] : 0.f;
        __syncthreads();
        sc[j] += ca; ss[j] += sa;
        __syncthreads();
    }
    const unsigned Tj = sc[j]; const float Sj = ss[j];
    const unsigned T0 = sc[0]; const float S0 = ss[0];

    __shared__ unsigned snp;
    if (j < 64) {
        unsigned v = (j < CPR) ? bcnt[(size_t)r * CPR + j].w : 0u;
        #pragma unroll
        for (int o = 32; o > 0; o >>= 1) v += __shfl_down(v, o);
        if (j == 0) snp = v;
    }
    __syncthreads();

    long long k = (long long)NEGPOS_ * (long long)snp;
    if (k > P_ - 1) k = P_ - 1;

    if (k <= 0)             { if (j == 0) rowS2[r] = 0.f; return; }
    if ((long long)T0 <= k) { if (j == 0) rowS2[r] = S0;  return; }

    const unsigned above = Tj - c;                  // strictly-higher-bin count
    if ((long long)above < k && k <= (long long)Tj) {   // unique boundary thread
        const unsigned rr = (unsigned)(k - above);
        rowS2[r] = (Sj - s) + (c ? s * (float)rr / (float)c : 0.f);
    }
}

// ---- K3: finalize ---------------------------------------------------------------
__global__ __launch_bounds__(256) void mb_final(
    const float4* __restrict__ bpart, const uint4* __restrict__ bcnt,
    const float* __restrict__ rowS2, float* __restrict__ out)
{
    const int t = threadIdx.x;
    float f0 = 0, f1 = 0, f2 = 0, ce = 0;
    unsigned u0 = 0, u1 = 0, u2 = 0, np = 0;
    for (int i = t; i < NBLK; i += 256) {
        const float4 bp = bpart[i]; const uint4 bc = bcnt[i];
        f0 += bp.x; f1 += bp.y; f2 += bp.z; ce += bp.w;
        u0 += bc.x; u1 += bc.y; u2 += bc.z; np += bc.w;
    }
    float s2 = (t < B_) ? rowS2[t] : 0.f;
    #pragma unroll
    for (int o = 32; o > 0; o >>= 1) {
        f0 += __shfl_down(f0, o); f1 += __shfl_down(f1, o);
        f2 += __shfl_down(f2, o); ce += __shfl_down(ce, o);
        s2 += __shfl_down(s2, o);
        u0 += __shfl_down(u0, o); u1 += __shfl_down(u1, o);
        u2 += __shfl_down(u2, o); np += __shfl_down(np, o);
    }
    __shared__ float rf[4][5];
    __shared__ unsigned ru[4][4];
    const int wid = t >> 6;
    if ((t & 63) == 0) {
        rf[wid][0] = f0; rf[wid][1] = f1; rf[wid][2] = f2; rf[wid][3] = ce; rf[wid][4] = s2;
        ru[wid][0] = u0; ru[wid][1] = u1; ru[wid][2] = u2; ru[wid][3] = np;
    }
    __syncthreads();
    if (t == 0) {
        float F0 = 0, F1 = 0, F2 = 0, CE = 0, S2 = 0;
        unsigned U0 = 0, U1 = 0, U2 = 0, NP = 0;
        #pragma unroll
        for (int w = 0; w < 4; ++w) {
            F0 += rf[w][0]; F1 += rf[w][1]; F2 += rf[w][2]; CE += rf[w][3]; S2 += rf[w][4];
            U0 += ru[w][0]; U1 += ru[w][1]; U2 += ru[w][2]; NP += ru[w][3];
        }
        const float nl = U0 ? (float)U0 : 1.f;
        const float n1 = U1 ? (float)U1 : 1.f;
        const float nd = U2 ? (float)U2 : 1.f;
        const float n  = NP ? (float)NP : 1.f;
        out[0] = F0 / nl;          // loss_l / nl
        out[1] = (CE + S2) / n;    // loss_conf / n
        out[2] = F1 / n1;          // loss_landm / n1
        out[3] = F2 / nd;          // loss_dpth / ndpth
    }
}

extern "C" void kernel_launch(void* const* d_in, const int* in_sizes, int n_in,
                              void* d_out, int out_size, void* d_ws, size_t ws_size,
                              hipStream_t stream) {
    const float* boxes_p = (const float*)d_in[0];
    const float* conf_p  = (const float*)d_in[1];
    const float* kpts_p  = (const float*)d_in[2];
    const float* dpth_p  = (const float*)d_in[3];
    const float* boxes_t = (const float*)d_in[4];
    const float* kypts_t = (const float*)d_in[5];
    const float* dpths_t = (const float*)d_in[6];
    const int*   label   = (const int*)d_in[7];
    float* out = (float*)d_out;

    uint8_t* ws = (uint8_t*)d_ws;
    uint2*  hist  = (uint2*)(ws + OFF_HIST);
    float4* bpart = (float4*)(ws + OFF_BPART);
    uint4*  bcnt  = (uint4*)(ws + OFF_BCNT);
    float*  rowS2 = (float*)(ws + OFF_ROWS2);

    mb_main<<<NBLK, 256, 0, stream>>>(conf_p, label, boxes_p, kpts_p, dpth_p,
                                      boxes_t, kypts_t, dpths_t, hist, bpart, bcnt);

    mb_select<<<B_, 512, 0, stream>>>(hist, bcnt, rowS2);

    mb_final<<<1, 256, 0, stream>>>(bpart, bcnt, rowS2, out);
}

// Round 7
// 48.250 us; speedup vs baseline: 1.5093x; 1.0165x over previous
//
#include <hip/hip_runtime.h>
#include <stdint.h>

constexpr int B_ = 64;
constexpr int P_ = 65536;
constexpr int NEGPOS_ = 7;
constexpr int NBINS = 512;          // linear bins of d = c1 - c0 over [-5, 5]
constexpr int CHUNK = 2048;         // anchors per K1 block (8/thread)
constexpr int CPR = P_ / CHUNK;     // 32
constexpr int NBLK = B_ * CPR;      // 2048

typedef int   iv4 __attribute__((ext_vector_type(4)));
typedef float fv4 __attribute__((ext_vector_type(4)));

__device__ __forceinline__ int bin_of(float d) {
    int b = (int)fmaf(d, 51.2f, 256.0f);
    return b < 0 ? 0 : (b > NBINS - 1 ? NBINS - 1 : b);
}
__device__ __forceinline__ float softplus(float x) {
    return fmaxf(x, 0.f) + log1pf(expf(-fabsf(x)));
}
__device__ __forceinline__ float smooth_l1(float t, float p) {
    float ad = fabsf(t - p);
    return ad < 1.0f ? 0.5f * ad * ad : ad - 0.5f;
}

// Workspace (every byte written before read, every call; NO memset needed)
constexpr size_t OFF_HC16  = 0;                                     // NBLK*NBINS u16 (2 MB)
constexpr size_t OFF_HSUM  = OFF_HC16 + (size_t)NBLK * NBINS * 2;   // NBLK*NBINS f32 (4 MB)
constexpr size_t OFF_BPART = OFF_HSUM + (size_t)NBLK * NBINS * 4;   // NBLK float4
constexpr size_t OFF_BCNT  = OFF_BPART + (size_t)NBLK * 16;         // NBLK uint4
constexpr size_t OFF_ROWS2 = OFF_BCNT + (size_t)NBLK * 16;          // 64 f32
constexpr size_t OFF_DONE  = OFF_ROWS2 + 256;                       // u32

// ---- K1: dense stream + LDS-compacted positives + per-block hist ---------------
__global__ __launch_bounds__(256, 8) void mb_main(
    const float* __restrict__ conf,    const int* __restrict__ label,
    const float* __restrict__ boxes_p, const float* __restrict__ kpts_p,
    const float* __restrict__ dpth_p,  const float* __restrict__ boxes_t,
    const float* __restrict__ kypts_t, const float* __restrict__ dpths_t,
    uint16_t* __restrict__ hc16, float* __restrict__ hsumg,
    float4* __restrict__ bpart, uint4* __restrict__ bcnt, unsigned* __restrict__ done)
{
    __shared__ unsigned hcnt[NBINS];
    __shared__ float    hsum[NBINS];
    __shared__ unsigned lpos[CHUNK];
    __shared__ unsigned lcount;
    __shared__ float    redf[4][4];
    __shared__ unsigned redu[4][4];

    const int blk = blockIdx.x, t = threadIdx.x;
    const int row = blk / CPR, chunk = blk % CPR;
    const int base = row * P_ + chunk * CHUNK;
    const int a0 = base + t * 4;
    const int a1 = base + 1024 + t * 4;

    // issue ALL dense loads first (in flight during LDS zeroing + barrier)
    const iv4 labA = __builtin_nontemporal_load((const iv4*)(label + a0));
    const iv4 labB = __builtin_nontemporal_load((const iv4*)(label + a1));
    const fv4* cpA = (const fv4*)(conf + 2 * (size_t)a0);
    const fv4* cpB = (const fv4*)(conf + 2 * (size_t)a1);
    const fv4 cA0 = __builtin_nontemporal_load(cpA);
    const fv4 cA1 = __builtin_nontemporal_load(cpA + 1);
    const fv4 cB0 = __builtin_nontemporal_load(cpB);
    const fv4 cB1 = __builtin_nontemporal_load(cpB + 1);

    hcnt[2 * t] = 0u; hcnt[2 * t + 1] = 0u;
    hsum[2 * t] = 0.f; hsum[2 * t + 1] = 0.f;
    if (t == 0) lcount = 0u;
    if (blk == 0 && t == 0)
        __hip_atomic_store(done, 0u, __ATOMIC_RELAXED, __HIP_MEMORY_SCOPE_AGENT);
    __syncthreads();

    float lce = 0.f; unsigned cp = 0;

    auto proc = [&](int lab, float d, int idx) {
        if (lab != 0) {
            cp++;
            lce += softplus(-d);                       // lse - c1
            lpos[atomicAdd(&lcount, 1u)] = (unsigned)idx;
        } else {
            const int b = bin_of(d);
            atomicAdd(&hcnt[b], 1u);
            atomicAdd(&hsum[b], softplus(d));          // lse - c0  (ds_add_f32)
        }
    };

    proc(labA.x, cA0.y - cA0.x, a0 + 0);
    proc(labA.y, cA0.w - cA0.z, a0 + 1);
    proc(labA.z, cA1.y - cA1.x, a0 + 2);
    proc(labA.w, cA1.w - cA1.z, a0 + 3);
    proc(labB.x, cB0.y - cB0.x, a1 + 0);
    proc(labB.y, cB0.w - cB0.z, a1 + 1);
    proc(labB.z, cB1.y - cB1.x, a1 + 2);
    proc(labB.w, cB1.w - cB1.z, a1 + 3);
    __syncthreads();   // lpos/lcount complete

    // positives: all lanes active, one batch of scattered loads
    float lb = 0.f, ll = 0.f, ld = 0.f;
    unsigned cb = 0, cl = 0, cd = 0;
    const unsigned n = lcount;
    for (unsigned s = t; s < n; s += 256) {
        const unsigned i = lpos[s];
        const float4 bt = ((const float4*)boxes_t)[i];
        const float4 bp = ((const float4*)boxes_p)[i];
        if (!__builtin_isnan(bt.x)) { cb++; lb += smooth_l1(bt.x, bp.x); }
        if (!__builtin_isnan(bt.y)) { cb++; lb += smooth_l1(bt.y, bp.y); }
        if (!__builtin_isnan(bt.z)) { cb++; lb += smooth_l1(bt.z, bp.z); }
        if (!__builtin_isnan(bt.w)) { cb++; lb += smooth_l1(bt.w, bp.w); }
        const float2* kt = (const float2*)kypts_t + (size_t)i * 5;
        const float2* kp = (const float2*)kpts_p  + (size_t)i * 5;
        #pragma unroll
        for (int e = 0; e < 5; ++e) {
            const float2 t2 = kt[e], p2 = kp[e];
            if (!__builtin_isnan(t2.x)) { cl++; ll += smooth_l1(t2.x, p2.x); }
            if (!__builtin_isnan(t2.y)) { cl++; ll += smooth_l1(t2.y, p2.y); }
        }
        const float2 dt = ((const float2*)dpths_t)[i];
        const float2 dp = ((const float2*)dpth_p)[i];
        if (!__builtin_isnan(dt.x)) { cd++; ld += smooth_l1(dt.x, dp.x); }
        if (!__builtin_isnan(dt.y)) { cd++; ld += smooth_l1(dt.y, dp.y); }
    }

    // block reduction of the 8 scalars (no atomics)
    #pragma unroll
    for (int o = 32; o > 0; o >>= 1) {
        lb  += __shfl_down(lb, o);  ll  += __shfl_down(ll, o);
        ld  += __shfl_down(ld, o);  lce += __shfl_down(lce, o);
        cb  += __shfl_down(cb, o);  cl  += __shfl_down(cl, o);
        cd  += __shfl_down(cd, o);  cp  += __shfl_down(cp, o);
    }
    const int wid = t >> 6;
    if ((t & 63) == 0) {
        redf[wid][0] = lb; redf[wid][1] = ll; redf[wid][2] = ld; redf[wid][3] = lce;
        redu[wid][0] = cb; redu[wid][1] = cl; redu[wid][2] = cd; redu[wid][3] = cp;
    }
    __syncthreads();
    if (t == 0) {
        float f0 = 0, f1 = 0, f2 = 0, f3 = 0; unsigned u0 = 0, u1 = 0, u2 = 0, u3 = 0;
        #pragma unroll
        for (int w = 0; w < 4; ++w) {
            f0 += redf[w][0]; f1 += redf[w][1]; f2 += redf[w][2]; f3 += redf[w][3];
            u0 += redu[w][0]; u1 += redu[w][1]; u2 += redu[w][2]; u3 += redu[w][3];
        }
        bpart[blk] = make_float4(f0, f1, f2, f3);   // l_box, l_lm, l_dp, l_ce
        bcnt[blk]  = make_uint4(u0, u1, u2, u3);    // c_box, c_lm, c_dp, c_pos
    }

    // flush per-block hist (plain coalesced stores; counts fit u16)
    *(ushort2*)(hc16 + (size_t)blk * NBINS + 2 * t) =
        make_ushort2((uint16_t)hcnt[2 * t], (uint16_t)hcnt[2 * t + 1]);
    *(float2*)(hsumg + (size_t)blk * NBINS + 2 * t) =
        make_float2(hsum[2 * t], hsum[2 * t + 1]);
}

// ---- K2: blocks 0..63 = per-row select; block 64 = finalize (spin on done) ------
__global__ __launch_bounds__(512) void mb_tail(
    const uint16_t* __restrict__ hc16, const float* __restrict__ hsumg,
    const float4* __restrict__ bpart, const uint4* __restrict__ bcnt,
    float* __restrict__ rowS2, unsigned* __restrict__ done, float* __restrict__ out)
{
    const int t = threadIdx.x;

    if (blockIdx.x < B_) {
        const int r = blockIdx.x, j = t;

        unsigned c = 0; float s = 0.f;
        const uint16_t* hb = hc16 + (size_t)r * CPR * NBINS + j;
        const float*    sb = hsumg + (size_t)r * CPR * NBINS + j;
        #pragma unroll 8
        for (int ch = 0; ch < CPR; ++ch) {          // coalesced across j
            c += hb[(size_t)ch * NBINS];
            s += sb[(size_t)ch * NBINS];
        }

        __shared__ unsigned sc[NBINS];
        __shared__ float    ss[NBINS];
        sc[j] = c; ss[j] = s;
        __syncthreads();
        for (int off = 1; off < NBINS; off <<= 1) { // inclusive suffix scan
            const unsigned ca = (j + off < NBINS) ? sc[j + off] : 0u;
            const float    sa = (j + off < NBINS) ? ss[j + off] : 0.f;
            __syncthreads();
            sc[j] += ca; ss[j] += sa;
            __syncthreads();
        }
        const unsigned Tj = sc[j]; const float Sj = ss[j];
        const unsigned T0 = sc[0]; const float S0 = ss[0];

        __shared__ unsigned snp;
        if (j < 64) {
            unsigned v = (j < CPR) ? bcnt[(size_t)r * CPR + j].w : 0u;
            #pragma unroll
            for (int o = 32; o > 0; o >>= 1) v += __shfl_down(v, o);
            if (j == 0) snp = v;
        }
        __syncthreads();

        long long k = (long long)NEGPOS_ * (long long)snp;
        if (k > P_ - 1) k = P_ - 1;

        if (k <= 0)                 { if (j == 0) rowS2[r] = 0.f; }
        else if ((long long)T0 <= k){ if (j == 0) rowS2[r] = S0;  }
        else {
            const unsigned above = Tj - c;          // strictly-higher-bin count
            if ((long long)above < k && k <= (long long)Tj) {   // unique thread
                const unsigned rr = (unsigned)(k - above);
                rowS2[r] = (Sj - s) + (c ? s * (float)rr / (float)c : 0.f);
            }
        }
        __syncthreads();
        if (j == 0)
            __hip_atomic_fetch_add(done, 1u, __ATOMIC_RELEASE, __HIP_MEMORY_SCOPE_AGENT);
    } else {
        // finalize block: reduce bpart/bcnt while selects run, then wait for rowS2
        float f0 = 0, f1 = 0, f2 = 0, ce = 0;
        unsigned u0 = 0, u1 = 0, u2 = 0, np = 0;
        for (int i = t; i < NBLK; i += 512) {
            const float4 bp = bpart[i]; const uint4 bc = bcnt[i];
            f0 += bp.x; f1 += bp.y; f2 += bp.z; ce += bp.w;
            u0 += bc.x; u1 += bc.y; u2 += bc.z; np += bc.w;
        }
        #pragma unroll
        for (int o = 32; o > 0; o >>= 1) {
            f0 += __shfl_down(f0, o); f1 += __shfl_down(f1, o);
            f2 += __shfl_down(f2, o); ce += __shfl_down(ce, o);
            u0 += __shfl_down(u0, o); u1 += __shfl_down(u1, o);
            u2 += __shfl_down(u2, o); np += __shfl_down(np, o);
        }
        __shared__ float rf[8][4];
        __shared__ unsigned ru[8][4];
        const int wid = t >> 6;
        if ((t & 63) == 0) {
            rf[wid][0] = f0; rf[wid][1] = f1; rf[wid][2] = f2; rf[wid][3] = ce;
            ru[wid][0] = u0; ru[wid][1] = u1; ru[wid][2] = u2; ru[wid][3] = np;
        }
        __syncthreads();

        if (t == 0) {
            while (__hip_atomic_load(done, __ATOMIC_ACQUIRE, __HIP_MEMORY_SCOPE_AGENT)
                   < (unsigned)B_) { }
        }
        __syncthreads();

        float s2 = 0.f;
        if (t < 64) {
            s2 = (t < B_) ? rowS2[t] : 0.f;
            #pragma unroll
            for (int o = 32; o > 0; o >>= 1) s2 += __shfl_down(s2, o);
        }
        if (t == 0) {
            float F0 = 0, F1 = 0, F2 = 0, CE = 0;
            unsigned U0 = 0, U1 = 0, U2 = 0, NP = 0;
            #pragma unroll
            for (int w = 0; w < 8; ++w) {
                F0 += rf[w][0]; F1 += rf[w][1]; F2 += rf[w][2]; CE += rf[w][3];
                U0 += ru[w][0]; U1 += ru[w][1]; U2 += ru[w][2]; NP += ru[w][3];
            }
            const float nl = U0 ? (float)U0 : 1.f;
            const float n1 = U1 ? (float)U1 : 1.f;
            const float nd = U2 ? (float)U2 : 1.f;
            const float n  = NP ? (float)NP : 1.f;
            out[0] = F0 / nl;          // loss_l / nl
            out[1] = (CE + s2) / n;    // loss_conf / n
            out[2] = F1 / n1;          // loss_landm / n1
            out[3] = F2 / nd;          // loss_dpth / ndpth
        }
    }
}

extern "C" void kernel_launch(void* const* d_in, const int* in_sizes, int n_in,
                              void* d_out, int out_size, void* d_ws, size_t ws_size,
                              hipStream_t stream) {
    const float* boxes_p = (const float*)d_in[0];
    const float* conf_p  = (const float*)d_in[1];
    const float* kpts_p  = (const float*)d_in[2];
    const float* dpth_p  = (const float*)d_in[3];
    const float* boxes_t = (const float*)d_in[4];
    const float* kypts_t = (const float*)d_in[5];
    const float* dpths_t = (const float*)d_in[6];
    const int*   label   = (const int*)d_in[7];
    float* out = (float*)d_out;

    uint8_t* ws = (uint8_t*)d_ws;
    uint16_t* hc16  = (uint16_t*)(ws + OFF_HC16);
    float*    hsumg = (float*)(ws + OFF_HSUM);
    float4*   bpart = (float4*)(ws + OFF_BPART);
    uint4*    bcnt  = (uint4*)(ws + OFF_BCNT);
    float*    rowS2 = (float*)(ws + OFF_ROWS2);
    unsigned* done  = (unsigned*)(ws + OFF_DONE);

    mb_main<<<NBLK, 256, 0, stream>>>(conf_p, label, boxes_p, kpts_p, dpth_p,
                                      boxes_t, kypts_t, dpths_t,
                                      hc16, hsumg, bpart, bcnt, done);

    mb_tail<<<B_ + 1, 512, 0, stream>>>(hc16, hsumg, bpart, bcnt, rowS2, done, out);
}